// Round 11
// baseline (102.572 us; speedup 1.0000x reference)
//
#include <hip/hip_runtime.h>
#include <hip/hip_bf16.h>
#include <stdint.h>

#define M_DIM 2048
#define N_DIM 4096
#define K_DIM 4096

#define NT 64  // K tiles of 64

typedef short short8 __attribute__((ext_vector_type(8)));
typedef float f32x4 __attribute__((ext_vector_type(4)));
typedef float f32x16 __attribute__((ext_vector_type(16)));

typedef __attribute__((address_space(1))) unsigned int gu32;
typedef __attribute__((address_space(3))) unsigned int lu32;

// f32 -> bf16 round-to-nearest-even
__device__ static inline unsigned short f32_to_bf16(float f) {
  union { float f; unsigned int u; } v; v.f = f;
  unsigned int u = v.u;
  u += 0x7FFFu + ((u >> 16) & 1u);
  return (unsigned short)(u >> 16);
}

// ---- x: f32 [M][K] -> bf16 [M][K] ----
__global__ void cvt_x_kernel(const float* __restrict__ in, unsigned short* __restrict__ out) {
  size_t i = ((size_t)blockIdx.x * blockDim.x + threadIdx.x) * 8;
  f32x4 a = *(const f32x4*)(in + i);
  f32x4 b = *(const f32x4*)(in + i + 4);
  short8 o;
  o[0] = (short)f32_to_bf16(a[0]); o[1] = (short)f32_to_bf16(a[1]);
  o[2] = (short)f32_to_bf16(a[2]); o[3] = (short)f32_to_bf16(a[3]);
  o[4] = (short)f32_to_bf16(b[0]); o[5] = (short)f32_to_bf16(b[1]);
  o[6] = (short)f32_to_bf16(b[2]); o[7] = (short)f32_to_bf16(b[3]);
  *(short8*)(out + i) = o;
}

// ---- w: f32 [K][N] -> bf16 Bt [N][K] ----
__global__ void transpose_cvt_w_kernel(const float* __restrict__ w, unsigned short* __restrict__ wt) {
  __shared__ unsigned short tile[64][64 + 8];
  int bn = blockIdx.x * 64;
  int bk = blockIdx.y * 64;
  int t = threadIdx.x;
  int c4 = (t & 15) * 4;
  int r0 = t >> 4;
#pragma unroll
  for (int p = 0; p < 4; ++p) {
    int r = r0 + p * 16;
    f32x4 v = *(const f32x4*)(w + (size_t)(bk + r) * N_DIM + bn + c4);
    tile[c4 + 0][r] = f32_to_bf16(v[0]);
    tile[c4 + 1][r] = f32_to_bf16(v[1]);
    tile[c4 + 2][r] = f32_to_bf16(v[2]);
    tile[c4 + 3][r] = f32_to_bf16(v[3]);
  }
  __syncthreads();
  int orow = t >> 2;
  int oc = (t & 3) * 16;
  short8 lo, hi;
#pragma unroll
  for (int j = 0; j < 8; ++j) {
    lo[j] = (short)tile[orow][oc + j];
    hi[j] = (short)tile[orow][oc + 8 + j];
  }
  unsigned short* op = wt + (size_t)(bn + orow) * K_DIM + bk + oc;
  *(short8*)(op) = lo;
  *(short8*)(op + 8) = hi;
}

// ======== GEMM (round 11): R4 skeleton + 32x32x16 MFMA fragments ========
// BM=128, BN=256, BK=64. 512 threads = 8 waves (2M x 4N), wave tile 64x64
// = 2x2 fragments of 32x32; K-tile = 4 k-steps of 16.
// Per wave per tile: 16 MFMA (was 32 with 16x16x32) at 1.20x pipe rate
// (2495 vs 2075 TF ubench) and 16 ds_read_b128 (unchanged bytes).
// Operand safety: A row=lane&31, k-chunk=lane>>5; B identical => same-psi
// permutation-invariant dot product for any hardware k-map bijection.
// C/D layout (m74/m101-verified): col=lane&31, row=(reg&3)+8(reg>>2)+4(lane>>5).
// Staging / XOR swizzle / 3-side rotation / vmcnt(6)+lgkmcnt(0)+s_barrier
// sync / grid remap: byte-identical to R4 (proven R3-R10).

__global__ __launch_bounds__(512) void gemm8_kernel(
    const unsigned short* __restrict__ A, const unsigned short* __restrict__ Bt,
    const float* __restrict__ bias, float* __restrict__ C) {
  __shared__ unsigned short smA[3 * 24576];  // 147456 B
  char* smemc = (char*)&smA[0];

  const int tid = threadIdx.x;
  const int lane = tid & 63;
  const int w = tid >> 6;
  const int wm = w >> 2, wn = w & 3;

  // 8x4 region remap for L2 locality (bijective over 256 blocks)
  const int id = blockIdx.x;
  const int x = id & 7, j = id >> 3;
  const int by = ((x >> 2) << 3) + (j >> 2);
  const int bx = ((x & 3) << 2) + (j & 3);
  const int r0 = by * 128, c0 = bx * 256;

  // ---- staging precompute (pre-swizzled global source, linear LDS dest) ----
  const int l8 = lane >> 3, l7 = lane & 7;
  const int chunkE = ((l7 ^ l8) << 3);  // swizzled k-chunk (bf16 elems), row&7 == l8
  const unsigned short* Ag = A + (size_t)(r0 + w * 16 + l8) * K_DIM + chunkE;
  const unsigned short* Bg = Bt + (size_t)(c0 + w * 32 + l8) * K_DIM + chunkE;
  const int aL0 = w * 2048;          // byte offset of wave's A chunk within side
  const int bL0 = 16384 + w * 4096;  // byte offset of wave's B chunk within side

#define GL(gp, ldsoff) __builtin_amdgcn_global_load_lds((gu32*)(gp), (lu32*)(smemc + (ldsoff)), 16, 0, 0)
#define STAGE_ALL(t, sb)                                               \
  do {                                                                 \
    GL(Ag + (size_t)(t) * 64, (sb) + aL0);                             \
    GL(Ag + (size_t)(t) * 64 + 8 * (size_t)K_DIM, (sb) + aL0 + 1024);  \
    GL(Bg + (size_t)(t) * 64, (sb) + bL0);                             \
    GL(Bg + (size_t)(t) * 64 + 8 * (size_t)K_DIM, (sb) + bL0 + 1024);  \
    GL(Bg + (size_t)(t) * 64 + 16 * (size_t)K_DIM, (sb) + bL0 + 2048); \
    GL(Bg + (size_t)(t) * 64 + 24 * (size_t)K_DIM, (sb) + bL0 + 3072); \
  } while (0)

  // ---- fragment-read precompute (ushort units within side) ----
  // frag (fm/fn, ks): row = base + frag*32 + (lane&31); chunk = ks*2 + (lane>>5)
  // slot = chunk ^ (row&7); row&7 == lane&7 (bases are multiples of 32).
  const int l31 = lane & 31, g5 = lane >> 5;
  const int aR = (wm * 64 + l31) * 64;         // A row base
  const int bR = 8192 + (wn * 64 + l31) * 64;  // B row base (B region at 16KB)
  int slotk[4];
#pragma unroll
  for (int ks = 0; ks < 4; ++ks) slotk[ks] = (((ks * 2 + g5) ^ l7) << 3);

  f32x16 acc[2][2] = {};

  // prologue: stage tiles 0 and 1
  STAGE_ALL(0, 0);
  STAGE_ALL(1, 49152);

  int cs = 0;  // side of tile t
  for (int t = 0; t < NT; ++t) {
    const int sE = cs * 24576;                       // compute side (ushorts)
    const int stB = (cs == 0 ? 2 : cs - 1) * 49152;  // stage side (bytes)
    const bool doStage = (t + 2) < NT;

    // per-wave completion of tile t's loads, published to all waves
    if (t < NT - 1) asm volatile("s_waitcnt vmcnt(6) lgkmcnt(0)" ::: "memory");
    else            asm volatile("s_waitcnt vmcnt(0) lgkmcnt(0)" ::: "memory");
    __builtin_amdgcn_sched_barrier(0);
    asm volatile("s_barrier" ::: "memory");

    // -------- body: 16 ds_read + 6 GL + 16 MFMA (32x32x16) --------
    short8 a[4][2], b[4][2];
#pragma unroll
    for (int ks = 0; ks < 2; ++ks) {
#pragma unroll
      for (int f = 0; f < 2; ++f) {
        a[ks][f] = *(const short8*)(smA + sE + aR + f * 2048 + slotk[ks]);
        b[ks][f] = *(const short8*)(smA + sE + bR + f * 2048 + slotk[ks]);
      }
    }
    if (doStage) STAGE_ALL(t + 2, stB);
#pragma unroll
    for (int ks = 2; ks < 4; ++ks) {
#pragma unroll
      for (int f = 0; f < 2; ++f) {
        a[ks][f] = *(const short8*)(smA + sE + aR + f * 2048 + slotk[ks]);
        b[ks][f] = *(const short8*)(smA + sE + bR + f * 2048 + slotk[ks]);
      }
    }

    __builtin_amdgcn_s_setprio(1);
#pragma unroll
    for (int ks = 0; ks < 4; ++ks)
#pragma unroll
      for (int fm = 0; fm < 2; ++fm)
#pragma unroll
        for (int fn = 0; fn < 2; ++fn)
          acc[fm][fn] = __builtin_amdgcn_mfma_f32_32x32x16_bf16(
              a[ks][fm], b[ks][fn], acc[fm][fn], 0, 0, 0);
    __builtin_amdgcn_s_setprio(0);

    cs = (cs == 2) ? 0 : cs + 1;
  }

  // ---- epilogue: fxp(y) + fxp(b), relu ----
  // C/D 32x32 map (m74/m101): col=lane&31, row=(reg&3)+8*(reg>>2)+4*(lane>>5)
  const float S = 65536.0f, IS = 1.0f / 65536.0f;
#pragma unroll
  for (int fn = 0; fn < 2; ++fn) {
    int gcol = c0 + wn * 64 + fn * 32 + l31;
    float bq = rintf(bias[gcol] * S) * IS;
#pragma unroll
    for (int fm = 0; fm < 2; ++fm) {
      int growb = r0 + wm * 64 + fm * 32 + 4 * g5;
#pragma unroll
      for (int reg = 0; reg < 16; ++reg) {
        int grow = growb + (reg & 3) + 8 * (reg >> 2);
        float t = rintf(acc[fm][fn][reg] * S) * IS + bq;
        t = t > 0.0f ? t : 0.0f;
        C[(size_t)grow * N_DIM + gcol] = t;
      }
    }
  }
#undef GL
#undef STAGE_ALL
}

// ---- fallback (small workspace): round-1 reg-staged kernel ----
__global__ __launch_bounds__(256, 2) void gemm_fb_kernel(
    const float* __restrict__ Xf, const float* __restrict__ Wf,
    const float* __restrict__ bias, float* __restrict__ C) {
  __shared__ unsigned short As[128][64];
  __shared__ unsigned short Bs[128][64];
  int tid = threadIdx.x;
  int lane = tid & 63;
  int wid = tid >> 6;
  int wr = wid >> 1, wc = wid & 1;
  int r0 = blockIdx.y * 128;
  int c0 = blockIdx.x * 128;
  f32x4 acc[4][4] = {};
  for (int kt = 0; kt < K_DIM / 64; ++kt) {
    __syncthreads();
    int ar = tid >> 1;
    int ac = (tid & 1) * 32;
    const float* xp = Xf + (size_t)(r0 + ar) * K_DIM + kt * 64 + ac;
#pragma unroll
    for (int jj = 0; jj < 8; ++jj) {
      f32x4 v = *(const f32x4*)(xp + jj * 4);
      As[ar][ac + jj * 4 + 0] = f32_to_bf16(v[0]);
      As[ar][ac + jj * 4 + 1] = f32_to_bf16(v[1]);
      As[ar][ac + jj * 4 + 2] = f32_to_bf16(v[2]);
      As[ar][ac + jj * 4 + 3] = f32_to_bf16(v[3]);
    }
    int bk_ = tid >> 2;
    int bc = (tid & 3) * 32;
    const float* wp = Wf + (size_t)(kt * 64 + bk_) * N_DIM + c0 + bc;
#pragma unroll
    for (int jj = 0; jj < 8; ++jj) {
      f32x4 v = *(const f32x4*)(wp + jj * 4);
      Bs[bc + jj * 4 + 0][bk_] = f32_to_bf16(v[0]);
      Bs[bc + jj * 4 + 1][bk_] = f32_to_bf16(v[1]);
      Bs[bc + jj * 4 + 2][bk_] = f32_to_bf16(v[2]);
      Bs[bc + jj * 4 + 3][bk_] = f32_to_bf16(v[3]);
    }
    __syncthreads();
#pragma unroll
    for (int ks = 0; ks < 2; ++ks) {
      int co = ks * 32 + (lane >> 4) * 8;
      int rA = wr * 64 + (lane & 15);
      int rB = wc * 64 + (lane & 15);
      short8 a[4], b[4];
#pragma unroll
      for (int m = 0; m < 4; ++m) a[m] = *(const short8*)&As[rA + m * 16][co];
#pragma unroll
      for (int n = 0; n < 4; ++n) b[n] = *(const short8*)&Bs[rB + n * 16][co];
#pragma unroll
      for (int m = 0; m < 4; ++m)
#pragma unroll
        for (int n = 0; n < 4; ++n)
          acc[m][n] = __builtin_amdgcn_mfma_f32_16x16x32_bf16(a[m], b[n], acc[m][n], 0, 0, 0);
    }
  }
  const float S = 65536.0f, IS = 1.0f / 65536.0f;
  int lr = (lane >> 4) * 4;
  int lc = lane & 15;
#pragma unroll
  for (int n = 0; n < 4; ++n) {
    int gcol = c0 + wc * 64 + n * 16 + lc;
    float bq = rintf(bias[gcol] * S) * IS;
#pragma unroll
    for (int m = 0; m < 4; ++m) {
      int grow = r0 + wr * 64 + m * 16 + lr;
      float* outp = C + (size_t)grow * N_DIM + gcol;
#pragma unroll
      for (int r = 0; r < 4; ++r) {
        float t = rintf(acc[m][n][r] * S) * IS + bq;
        t = t > 0.0f ? t : 0.0f;
        outp[(size_t)r * N_DIM] = t;
      }
    }
  }
}

extern "C" void kernel_launch(void* const* d_in, const int* in_sizes, int n_in,
                              void* d_out, int out_size, void* d_ws, size_t ws_size,
                              hipStream_t stream) {
  const float* x = (const float*)d_in[0];
  const float* w = (const float*)d_in[1];
  const float* b = (const float*)d_in[2];
  float* out = (float*)d_out;

  size_t needA = (size_t)M_DIM * K_DIM * sizeof(unsigned short);
  size_t needB = (size_t)K_DIM * N_DIM * sizeof(unsigned short);

  if (ws_size >= needA + needB) {
    unsigned short* Abf = (unsigned short*)d_ws;
    unsigned short* Btbf = (unsigned short*)((char*)d_ws + needA);
    cvt_x_kernel<<<(M_DIM * (size_t)K_DIM / 8 + 255) / 256, 256, 0, stream>>>(x, Abf);
    transpose_cvt_w_kernel<<<dim3(N_DIM / 64, K_DIM / 64), 256, 0, stream>>>(w, Btbf);
    gemm8_kernel<<<256, 512, 0, stream>>>(Abf, Btbf, b, out);
  } else {
    gemm_fb_kernel<<<dim3(N_DIM / 128, M_DIM / 128), 256, 0, stream>>>(x, w, b, out);
  }
}

// Round 12
// 92.209 us; speedup vs baseline: 1.1124x; 1.1124x over previous
//
#include <hip/hip_runtime.h>
#include <hip/hip_bf16.h>
#include <stdint.h>

#define M_DIM 2048
#define N_DIM 4096
#define K_DIM 4096

#define NT 64  // K tiles of 64

typedef short short8 __attribute__((ext_vector_type(8)));
typedef float f32x4 __attribute__((ext_vector_type(4)));

typedef __attribute__((address_space(1))) unsigned int gu32;
typedef __attribute__((address_space(3))) unsigned int lu32;

// f32 -> bf16 round-to-nearest-even
__device__ static inline unsigned short f32_to_bf16(float f) {
  union { float f; unsigned int u; } v; v.f = f;
  unsigned int u = v.u;
  u += 0x7FFFu + ((u >> 16) & 1u);
  return (unsigned short)(u >> 16);
}

// ---- x: f32 [M][K] -> bf16 [M][K] ----
__global__ void cvt_x_kernel(const float* __restrict__ in, unsigned short* __restrict__ out) {
  size_t i = ((size_t)blockIdx.x * blockDim.x + threadIdx.x) * 8;
  f32x4 a = *(const f32x4*)(in + i);
  f32x4 b = *(const f32x4*)(in + i + 4);
  short8 o;
  o[0] = (short)f32_to_bf16(a[0]); o[1] = (short)f32_to_bf16(a[1]);
  o[2] = (short)f32_to_bf16(a[2]); o[3] = (short)f32_to_bf16(a[3]);
  o[4] = (short)f32_to_bf16(b[0]); o[5] = (short)f32_to_bf16(b[1]);
  o[6] = (short)f32_to_bf16(b[2]); o[7] = (short)f32_to_bf16(b[3]);
  *(short8*)(out + i) = o;
}

// ---- w: f32 [K][N] -> bf16 Bt [N][K] ----
__global__ void transpose_cvt_w_kernel(const float* __restrict__ w, unsigned short* __restrict__ wt) {
  __shared__ unsigned short tile[64][64 + 8];
  int bn = blockIdx.x * 64;
  int bk = blockIdx.y * 64;
  int t = threadIdx.x;
  int c4 = (t & 15) * 4;
  int r0 = t >> 4;
#pragma unroll
  for (int p = 0; p < 4; ++p) {
    int r = r0 + p * 16;
    f32x4 v = *(const f32x4*)(w + (size_t)(bk + r) * N_DIM + bn + c4);
    tile[c4 + 0][r] = f32_to_bf16(v[0]);
    tile[c4 + 1][r] = f32_to_bf16(v[1]);
    tile[c4 + 2][r] = f32_to_bf16(v[2]);
    tile[c4 + 3][r] = f32_to_bf16(v[3]);
  }
  __syncthreads();
  int orow = t >> 2;
  int oc = (t & 3) * 16;
  short8 lo, hi;
#pragma unroll
  for (int j = 0; j < 8; ++j) {
    lo[j] = (short)tile[orow][oc + j];
    hi[j] = (short)tile[orow][oc + 8 + j];
  }
  unsigned short* op = wt + (size_t)(bn + orow) * K_DIM + bk + oc;
  *(short8*)(op) = lo;
  *(short8*)(op + 8) = hi;
}

// ======= GEMM (round 12): R4 skeleton + cross-wave phase stagger =======
// BM=128, BN=256, BK=64. 512 threads = 8 waves (2M x 4N), wave tile 64x64,
// 16x16x32 MFMA (R11's 32x32 shape had 4cyc/read bank conflicts - reverted).
// DIAGNOSIS (R4 ledger): port-time 1536 + MFMA-time 1240 = 2776 ~= measured
// 2719 cyc/tile. Barrier-lockstepped waves alternate {all-read} / {all-MFMA}
// phases; port and MFMA pipe never overlap. All prior levers kept waves
// phase-aligned => null.
// FIX: wave->SIMD is round-robin (SIMD s hosts waves s and s+4). Waves 0-3
// process ks0 then ks1; waves 4-7 process ks1 then ks0. Each SIMD has one
// wave reading while its partner MFMAs -> port streams concurrently with
// the MFMA pipe by construction. Both orders read the same published tile
// between the same barriers; per-wave ks accumulation order is FP-benign;
// next-tile-top lgkmcnt(0) covers both groups (WAR invariant intact).
// Everything else (staging, swizzle, 3-side rotation, vmcnt(6) sync, grid
// remap, epilogue) byte-identical to the proven R4/R7 kernel.

__global__ __launch_bounds__(512) void gemm8_kernel(
    const unsigned short* __restrict__ A, const unsigned short* __restrict__ Bt,
    const float* __restrict__ bias, float* __restrict__ C) {
  __shared__ unsigned short smA[3 * 24576];  // 147456 B
  char* smemc = (char*)&smA[0];

  const int tid = threadIdx.x;
  const int lane = tid & 63;
  const int w = tid >> 6;
  const int wm = w >> 2, wn = w & 3;

  // 8x4 region remap for L2 locality (bijective over 256 blocks)
  const int id = blockIdx.x;
  const int x = id & 7, j = id >> 3;
  const int by = ((x >> 2) << 3) + (j >> 2);
  const int bx = ((x & 3) << 2) + (j & 3);
  const int r0 = by * 128, c0 = bx * 256;

  // ---- staging precompute (pre-swizzled global source, linear LDS dest) ----
  const int l8 = lane >> 3, l7 = lane & 7;
  const int chunkE = ((l7 ^ l8) << 3);  // swizzled k-chunk (bf16 elems), row&7 == l8
  const unsigned short* Ag = A + (size_t)(r0 + w * 16 + l8) * K_DIM + chunkE;
  const unsigned short* Bg = Bt + (size_t)(c0 + w * 32 + l8) * K_DIM + chunkE;
  const int aL0 = w * 2048;          // byte offset of wave's A chunk within side
  const int bL0 = 16384 + w * 4096;  // byte offset of wave's B chunk within side

#define GL(gp, ldsoff) __builtin_amdgcn_global_load_lds((gu32*)(gp), (lu32*)(smemc + (ldsoff)), 16, 0, 0)
#define STAGE_ALL(t, sb)                                               \
  do {                                                                 \
    GL(Ag + (size_t)(t) * 64, (sb) + aL0);                             \
    GL(Ag + (size_t)(t) * 64 + 8 * (size_t)K_DIM, (sb) + aL0 + 1024);  \
    GL(Bg + (size_t)(t) * 64, (sb) + bL0);                             \
    GL(Bg + (size_t)(t) * 64 + 8 * (size_t)K_DIM, (sb) + bL0 + 1024);  \
    GL(Bg + (size_t)(t) * 64 + 16 * (size_t)K_DIM, (sb) + bL0 + 2048); \
    GL(Bg + (size_t)(t) * 64 + 24 * (size_t)K_DIM, (sb) + bL0 + 3072); \
  } while (0)

  // ---- fragment-read precompute: 12 base pointers (side x ks x {A,B}) ----
  const int l15 = lane & 15, hi = lane >> 4;
  const int aR = (wm * 64 + l15) * 64;         // A row base (ushorts)
  const int bR = 8192 + (wn * 64 + l15) * 64;  // B row base (B region at 16KB)
  const int slot0 = ((hi ^ l7) << 3);          // ks=0: chunk hi at slot hi^(row&7)
  const int slot1 = (((4 + hi) ^ l7) << 3);    // ks=1: chunk 4+hi
  const unsigned short* pA0s0 = smA + 0 * 24576 + aR + slot0;
  const unsigned short* pA1s0 = smA + 1 * 24576 + aR + slot0;
  const unsigned short* pA2s0 = smA + 2 * 24576 + aR + slot0;
  const unsigned short* pA0s1 = smA + 0 * 24576 + aR + slot1;
  const unsigned short* pA1s1 = smA + 1 * 24576 + aR + slot1;
  const unsigned short* pA2s1 = smA + 2 * 24576 + aR + slot1;
  const unsigned short* pB0s0 = smA + 0 * 24576 + bR + slot0;
  const unsigned short* pB1s0 = smA + 1 * 24576 + bR + slot0;
  const unsigned short* pB2s0 = smA + 2 * 24576 + bR + slot0;
  const unsigned short* pB0s1 = smA + 0 * 24576 + bR + slot1;
  const unsigned short* pB1s1 = smA + 1 * 24576 + bR + slot1;
  const unsigned short* pB2s1 = smA + 2 * 24576 + bR + slot1;

  f32x4 acc[4][4] = {};

  // prologue: stage tiles 0 and 1
  STAGE_ALL(0, 0);
  STAGE_ALL(1, 49152);

  const bool grpB = (w >= 4);  // SIMD s hosts waves s (grpA) and s+4 (grpB)

  int cs = 0;  // side of tile t
  for (int t = 0; t < NT; ++t) {
    const int stB = (cs == 0 ? 2 : cs - 1) * 49152;  // stage side (bytes)
    const bool doStage = (t + 2) < NT;

    const unsigned short* pAs0 = (cs == 0) ? pA0s0 : (cs == 1) ? pA1s0 : pA2s0;
    const unsigned short* pAs1 = (cs == 0) ? pA0s1 : (cs == 1) ? pA1s1 : pA2s1;
    const unsigned short* pBs0 = (cs == 0) ? pB0s0 : (cs == 1) ? pB1s0 : pB2s0;
    const unsigned short* pBs1 = (cs == 0) ? pB0s1 : (cs == 1) ? pB1s1 : pB2s1;

    // per-wave completion of tile t's loads, published to all waves
    if (t < NT - 1) asm volatile("s_waitcnt vmcnt(6) lgkmcnt(0)" ::: "memory");
    else            asm volatile("s_waitcnt vmcnt(0) lgkmcnt(0)" ::: "memory");
    __builtin_amdgcn_sched_barrier(0);
    asm volatile("s_barrier" ::: "memory");

    // -------- body: staggered {read half / MFMA half} by wave group --------
    if (!grpB) {
      // waves 0-3: ks0 first
      short8 a0[4], b0[4];
#pragma unroll
      for (int m = 0; m < 4; ++m) a0[m] = *(const short8*)(pAs0 + m * 1024);
#pragma unroll
      for (int n = 0; n < 4; ++n) b0[n] = *(const short8*)(pBs0 + n * 1024);
      if (doStage) STAGE_ALL(t + 2, stB);
      __builtin_amdgcn_s_setprio(1);
#pragma unroll
      for (int m = 0; m < 4; ++m)
#pragma unroll
        for (int n = 0; n < 4; ++n)
          acc[m][n] = __builtin_amdgcn_mfma_f32_16x16x32_bf16(a0[m], b0[n], acc[m][n], 0, 0, 0);
      __builtin_amdgcn_s_setprio(0);
      short8 a1[4], b1[4];
#pragma unroll
      for (int m = 0; m < 4; ++m) a1[m] = *(const short8*)(pAs1 + m * 1024);
#pragma unroll
      for (int n = 0; n < 4; ++n) b1[n] = *(const short8*)(pBs1 + n * 1024);
      __builtin_amdgcn_s_setprio(1);
#pragma unroll
      for (int m = 0; m < 4; ++m)
#pragma unroll
        for (int n = 0; n < 4; ++n)
          acc[m][n] = __builtin_amdgcn_mfma_f32_16x16x32_bf16(a1[m], b1[n], acc[m][n], 0, 0, 0);
      __builtin_amdgcn_s_setprio(0);
    } else {
      // waves 4-7: ks1 first (SIMD partner is in its read phase while we MFMA)
      short8 a1[4], b1[4];
#pragma unroll
      for (int m = 0; m < 4; ++m) a1[m] = *(const short8*)(pAs1 + m * 1024);
#pragma unroll
      for (int n = 0; n < 4; ++n) b1[n] = *(const short8*)(pBs1 + n * 1024);
      if (doStage) STAGE_ALL(t + 2, stB);
      __builtin_amdgcn_s_setprio(1);
#pragma unroll
      for (int m = 0; m < 4; ++m)
#pragma unroll
        for (int n = 0; n < 4; ++n)
          acc[m][n] = __builtin_amdgcn_mfma_f32_16x16x32_bf16(a1[m], b1[n], acc[m][n], 0, 0, 0);
      __builtin_amdgcn_s_setprio(0);
      short8 a0[4], b0[4];
#pragma unroll
      for (int m = 0; m < 4; ++m) a0[m] = *(const short8*)(pAs0 + m * 1024);
#pragma unroll
      for (int n = 0; n < 4; ++n) b0[n] = *(const short8*)(pBs0 + n * 1024);
      __builtin_amdgcn_s_setprio(1);
#pragma unroll
      for (int m = 0; m < 4; ++m)
#pragma unroll
        for (int n = 0; n < 4; ++n)
          acc[m][n] = __builtin_amdgcn_mfma_f32_16x16x32_bf16(a0[m], b0[n], acc[m][n], 0, 0, 0);
      __builtin_amdgcn_s_setprio(0);
    }

    cs = (cs == 2) ? 0 : cs + 1;
  }

  // ---- epilogue: fxp(y) + fxp(b), relu ----
  const float S = 65536.0f, IS = 1.0f / 65536.0f;
  const int lr = hi * 4;  // C/D: row=(lane>>4)*4+reg, col=lane&15
#pragma unroll
  for (int n = 0; n < 4; ++n) {
    int gcol = c0 + wn * 64 + n * 16 + l15;
    float bq = rintf(bias[gcol] * S) * IS;
#pragma unroll
    for (int m = 0; m < 4; ++m) {
      int grow = r0 + wm * 64 + m * 16 + lr;
      float* outp = C + (size_t)grow * N_DIM + gcol;
#pragma unroll
      for (int r = 0; r < 4; ++r) {
        float t = rintf(acc[m][n][r] * S) * IS + bq;
        t = t > 0.0f ? t : 0.0f;
        outp[(size_t)r * N_DIM] = t;
      }
    }
  }
#undef GL
#undef STAGE_ALL
}

// ---- fallback (small workspace): round-1 reg-staged kernel ----
__global__ __launch_bounds__(256, 2) void gemm_fb_kernel(
    const float* __restrict__ Xf, const float* __restrict__ Wf,
    const float* __restrict__ bias, float* __restrict__ C) {
  __shared__ unsigned short As[128][64];
  __shared__ unsigned short Bs[128][64];
  int tid = threadIdx.x;
  int lane = tid & 63;
  int wid = tid >> 6;
  int wr = wid >> 1, wc = wid & 1;
  int r0 = blockIdx.y * 128;
  int c0 = blockIdx.x * 128;
  f32x4 acc[4][4] = {};
  for (int kt = 0; kt < K_DIM / 64; ++kt) {
    __syncthreads();
    int ar = tid >> 1;
    int ac = (tid & 1) * 32;
    const float* xp = Xf + (size_t)(r0 + ar) * K_DIM + kt * 64 + ac;
#pragma unroll
    for (int jj = 0; jj < 8; ++jj) {
      f32x4 v = *(const f32x4*)(xp + jj * 4);
      As[ar][ac + jj * 4 + 0] = f32_to_bf16(v[0]);
      As[ar][ac + jj * 4 + 1] = f32_to_bf16(v[1]);
      As[ar][ac + jj * 4 + 2] = f32_to_bf16(v[2]);
      As[ar][ac + jj * 4 + 3] = f32_to_bf16(v[3]);
    }
    int bk_ = tid >> 2;
    int bc = (tid & 3) * 32;
    const float* wp = Wf + (size_t)(kt * 64 + bk_) * N_DIM + c0 + bc;
#pragma unroll
    for (int jj = 0; jj < 8; ++jj) {
      f32x4 v = *(const f32x4*)(wp + jj * 4);
      Bs[bc + jj * 4 + 0][bk_] = f32_to_bf16(v[0]);
      Bs[bc + jj * 4 + 1][bk_] = f32_to_bf16(v[1]);
      Bs[bc + jj * 4 + 2][bk_] = f32_to_bf16(v[2]);
      Bs[bc + jj * 4 + 3][bk_] = f32_to_bf16(v[3]);
    }
    __syncthreads();
#pragma unroll
    for (int ks = 0; ks < 2; ++ks) {
      int co = ks * 32 + (lane >> 4) * 8;
      int rA = wr * 64 + (lane & 15);
      int rB = wc * 64 + (lane & 15);
      short8 a[4], b[4];
#pragma unroll
      for (int m = 0; m < 4; ++m) a[m] = *(const short8*)&As[rA + m * 16][co];
#pragma unroll
      for (int n = 0; n < 4; ++n) b[n] = *(const short8*)&Bs[rB + n * 16][co];
#pragma unroll
      for (int m = 0; m < 4; ++m)
#pragma unroll
        for (int n = 0; n < 4; ++n)
          acc[m][n] = __builtin_amdgcn_mfma_f32_16x16x32_bf16(a[m], b[n], acc[m][n], 0, 0, 0);
    }
  }
  const float S = 65536.0f, IS = 1.0f / 65536.0f;
  int lr = (lane >> 4) * 4;
  int lc = lane & 15;
#pragma unroll
  for (int n = 0; n < 4; ++n) {
    int gcol = c0 + wc * 64 + n * 16 + lc;
    float bq = rintf(bias[gcol] * S) * IS;
#pragma unroll
    for (int m = 0; m < 4; ++m) {
      int grow = r0 + wr * 64 + m * 16 + lr;
      float* outp = C + (size_t)grow * N_DIM + gcol;
#pragma unroll
      for (int r = 0; r < 4; ++r) {
        float t = rintf(acc[m][n][r] * S) * IS + bq;
        t = t > 0.0f ? t : 0.0f;
        outp[(size_t)r * N_DIM] = t;
      }
    }
  }
}

extern "C" void kernel_launch(void* const* d_in, const int* in_sizes, int n_in,
                              void* d_out, int out_size, void* d_ws, size_t ws_size,
                              hipStream_t stream) {
  const float* x = (const float*)d_in[0];
  const float* w = (const float*)d_in[1];
  const float* b = (const float*)d_in[2];
  float* out = (float*)d_out;

  size_t needA = (size_t)M_DIM * K_DIM * sizeof(unsigned short);
  size_t needB = (size_t)K_DIM * N_DIM * sizeof(unsigned short);

  if (ws_size >= needA + needB) {
    unsigned short* Abf = (unsigned short*)d_ws;
    unsigned short* Btbf = (unsigned short*)((char*)d_ws + needA);
    cvt_x_kernel<<<(M_DIM * (size_t)K_DIM / 8 + 255) / 256, 256, 0, stream>>>(x, Abf);
    transpose_cvt_w_kernel<<<dim3(N_DIM / 64, K_DIM / 64), 256, 0, stream>>>(w, Btbf);
    gemm8_kernel<<<256, 512, 0, stream>>>(Abf, Btbf, b, out);
  } else {
    gemm_fb_kernel<<<dim3(N_DIM / 128, M_DIM / 128), 256, 0, stream>>>(x, w, b, out);
  }
}

// Round 13
// 86.790 us; speedup vs baseline: 1.1818x; 1.0624x over previous
//
#include <hip/hip_runtime.h>
#include <hip/hip_bf16.h>
#include <stdint.h>

#define M_DIM 2048
#define N_DIM 4096
#define K_DIM 4096

#define NT 64  // K tiles of 64

typedef short short8 __attribute__((ext_vector_type(8)));
typedef float f32x4 __attribute__((ext_vector_type(4)));

typedef __attribute__((address_space(1))) unsigned int gu32;
typedef __attribute__((address_space(3))) unsigned int lu32;

// f32 -> bf16 round-to-nearest-even
__device__ static inline unsigned short f32_to_bf16(float f) {
  union { float f; unsigned int u; } v; v.f = f;
  unsigned int u = v.u;
  u += 0x7FFFu + ((u >> 16) & 1u);
  return (unsigned short)(u >> 16);
}

// ---- fused prep: blocks [0,4096) convert x; [4096,8192) transpose+convert w ----
// cvt part: x f32 [M][K] -> bf16 [M][K], 8 elems/thread.
// transpose part: w f32 [K][N] -> bf16 Bt [N][K] via 64x64 LDS tile.
__global__ void prep_kernel(const float* __restrict__ x, unsigned short* __restrict__ xa,
                            const float* __restrict__ wsrc, unsigned short* __restrict__ wt) {
  __shared__ unsigned short tile[64][64 + 8];
  int bid = blockIdx.x;
  int t = threadIdx.x;
  if (bid < 4096) {
    size_t i = ((size_t)bid * 256 + t) * 8;
    f32x4 a = *(const f32x4*)(x + i);
    f32x4 b = *(const f32x4*)(x + i + 4);
    short8 o;
    o[0] = (short)f32_to_bf16(a[0]); o[1] = (short)f32_to_bf16(a[1]);
    o[2] = (short)f32_to_bf16(a[2]); o[3] = (short)f32_to_bf16(a[3]);
    o[4] = (short)f32_to_bf16(b[0]); o[5] = (short)f32_to_bf16(b[1]);
    o[6] = (short)f32_to_bf16(b[2]); o[7] = (short)f32_to_bf16(b[3]);
    *(short8*)(xa + i) = o;
    return;
  }
  int b2 = bid - 4096;
  int bn = (b2 & 63) * 64;  // n block
  int bk = (b2 >> 6) * 64;  // k block
  int c4 = (t & 15) * 4;
  int r0 = t >> 4;
#pragma unroll
  for (int p = 0; p < 4; ++p) {
    int r = r0 + p * 16;
    f32x4 v = *(const f32x4*)(wsrc + (size_t)(bk + r) * N_DIM + bn + c4);
    tile[c4 + 0][r] = f32_to_bf16(v[0]);
    tile[c4 + 1][r] = f32_to_bf16(v[1]);
    tile[c4 + 2][r] = f32_to_bf16(v[2]);
    tile[c4 + 3][r] = f32_to_bf16(v[3]);
  }
  __syncthreads();
  int orow = t >> 2;
  int oc = (t & 3) * 16;
  short8 lo, hi;
#pragma unroll
  for (int j = 0; j < 8; ++j) {
    lo[j] = (short)tile[orow][oc + j];
    hi[j] = (short)tile[orow][oc + 8 + j];
  }
  unsigned short* op = wt + (size_t)(bn + orow) * K_DIM + bk + oc;
  *(short8*)(op) = lo;
  *(short8*)(op + 8) = hi;
}

// ====== GEMM (round 13): R4 best-measured body, setprio removed ======
// BM=128, BN=256, BK=64. 512 threads = 8 waves (2M x 4N), wave tile 64x64.
// LDS: 3 sides x 48KB. Side t%3; stage t+2 into (t-1)%3 during body t.
// ONE sync point per tile: {vmcnt(6) lgkmcnt(0); sched_barrier; s_barrier},
// merged body {16 ds_read + 6 global_load_lds + 32 MFMA}.
// setprio dropped per m190 (-14 TF@8k on lockstep GEMM; R12 proved no
// role-split exists here for it to arbitrate).
// R3-R12 ledger: barrier count, traffic, routing, blocks/CU, SGB, windows,
// MFMA shape, stagger all null -> structure pinned ~2700 cyc/tile
// (port-completion 1536 + MFMA tail + sync skew). 949 TF = m97-family
// ceiling; 256^2 deep pipelines can't fill the chip at M=2048.

__global__ __launch_bounds__(512) void gemm8_kernel(
    const unsigned short* __restrict__ A, const unsigned short* __restrict__ Bt,
    const float* __restrict__ bias, float* __restrict__ C) {
  __shared__ unsigned short smA[3 * 24576];  // 147456 B
  char* smemc = (char*)&smA[0];

  const int tid = threadIdx.x;
  const int lane = tid & 63;
  const int w = tid >> 6;
  const int wm = w >> 2, wn = w & 3;

  // 8x4 region remap for L2 locality (bijective over 256 blocks)
  const int id = blockIdx.x;
  const int x = id & 7, j = id >> 3;
  const int by = ((x >> 2) << 3) + (j >> 2);
  const int bx = ((x & 3) << 2) + (j & 3);
  const int r0 = by * 128, c0 = bx * 256;

  // ---- staging precompute (pre-swizzled global source, linear LDS dest) ----
  const int l8 = lane >> 3, l7 = lane & 7;
  const int chunkE = ((l7 ^ l8) << 3);  // swizzled k-chunk (bf16 elems), row&7 == l8
  const unsigned short* Ag = A + (size_t)(r0 + w * 16 + l8) * K_DIM + chunkE;
  const unsigned short* Bg = Bt + (size_t)(c0 + w * 32 + l8) * K_DIM + chunkE;
  const int aL0 = w * 2048;          // byte offset of wave's A chunk within side
  const int bL0 = 16384 + w * 4096;  // byte offset of wave's B chunk within side

#define GL(gp, ldsoff) __builtin_amdgcn_global_load_lds((gu32*)(gp), (lu32*)(smemc + (ldsoff)), 16, 0, 0)
#define STAGE_ALL(t, sb)                                               \
  do {                                                                 \
    GL(Ag + (size_t)(t) * 64, (sb) + aL0);                             \
    GL(Ag + (size_t)(t) * 64 + 8 * (size_t)K_DIM, (sb) + aL0 + 1024);  \
    GL(Bg + (size_t)(t) * 64, (sb) + bL0);                             \
    GL(Bg + (size_t)(t) * 64 + 8 * (size_t)K_DIM, (sb) + bL0 + 1024);  \
    GL(Bg + (size_t)(t) * 64 + 16 * (size_t)K_DIM, (sb) + bL0 + 2048); \
    GL(Bg + (size_t)(t) * 64 + 24 * (size_t)K_DIM, (sb) + bL0 + 3072); \
  } while (0)

  // ---- fragment-read precompute (ushort units within side) ----
  const int l15 = lane & 15, hi = lane >> 4;
  const int aR = (wm * 64 + l15) * 64;         // A row base
  const int bR = 8192 + (wn * 64 + l15) * 64;  // B row base (B region at 16KB)
  const int slot0 = ((hi ^ l7) << 3);          // ks=0: chunk hi at slot hi^(row&7)
  const int slot1 = (((4 + hi) ^ l7) << 3);    // ks=1: chunk 4+hi

  f32x4 acc[4][4] = {};

  // prologue: stage tiles 0 and 1
  STAGE_ALL(0, 0);
  STAGE_ALL(1, 49152);

  int cs = 0;  // side of tile t
  for (int t = 0; t < NT; ++t) {
    const int sE = cs * 24576;                       // compute side (ushorts)
    const int stB = (cs == 0 ? 2 : cs - 1) * 49152;  // stage side (bytes)
    const bool doStage = (t + 2) < NT;

    // single sync point per tile: my loads for tile t landed (vmcnt),
    // my side-(t-1) ds_reads complete (lgkmcnt), publish to all waves.
    if (t < NT - 1) asm volatile("s_waitcnt vmcnt(6) lgkmcnt(0)" ::: "memory");
    else            asm volatile("s_waitcnt vmcnt(0) lgkmcnt(0)" ::: "memory");
    __builtin_amdgcn_sched_barrier(0);
    asm volatile("s_barrier" ::: "memory");

    // -------- merged body: reads + stage + MFMA, compiler-interleaved ----
    short8 a0[4], b0[4], a1[4], b1[4];
#pragma unroll
    for (int m = 0; m < 4; ++m) a0[m] = *(const short8*)(smA + sE + aR + m * 1024 + slot0);
#pragma unroll
    for (int n = 0; n < 4; ++n) b0[n] = *(const short8*)(smA + sE + bR + n * 1024 + slot0);
    if (doStage) STAGE_ALL(t + 2, stB);
#pragma unroll
    for (int m = 0; m < 4; ++m) a1[m] = *(const short8*)(smA + sE + aR + m * 1024 + slot1);
#pragma unroll
    for (int n = 0; n < 4; ++n) b1[n] = *(const short8*)(smA + sE + bR + n * 1024 + slot1);

#pragma unroll
    for (int m = 0; m < 4; ++m)
#pragma unroll
      for (int n = 0; n < 4; ++n)
        acc[m][n] = __builtin_amdgcn_mfma_f32_16x16x32_bf16(a0[m], b0[n], acc[m][n], 0, 0, 0);
#pragma unroll
    for (int m = 0; m < 4; ++m)
#pragma unroll
      for (int n = 0; n < 4; ++n)
        acc[m][n] = __builtin_amdgcn_mfma_f32_16x16x32_bf16(a1[m], b1[n], acc[m][n], 0, 0, 0);

    cs = (cs == 2) ? 0 : cs + 1;
  }

  // ---- epilogue: fxp(y) + fxp(b), relu ----
  const float S = 65536.0f, IS = 1.0f / 65536.0f;
  const int lr = hi * 4;  // C/D: row=(lane>>4)*4+reg, col=lane&15
#pragma unroll
  for (int n = 0; n < 4; ++n) {
    int gcol = c0 + wn * 64 + n * 16 + l15;
    float bq = rintf(bias[gcol] * S) * IS;
#pragma unroll
    for (int m = 0; m < 4; ++m) {
      int grow = r0 + wm * 64 + m * 16 + lr;
      float* outp = C + (size_t)grow * N_DIM + gcol;
#pragma unroll
      for (int r = 0; r < 4; ++r) {
        float t = rintf(acc[m][n][r] * S) * IS + bq;
        t = t > 0.0f ? t : 0.0f;
        outp[(size_t)r * N_DIM] = t;
      }
    }
  }
#undef GL
#undef STAGE_ALL
}

// ---- fallback (small workspace): round-1 reg-staged kernel ----
__global__ __launch_bounds__(256, 2) void gemm_fb_kernel(
    const float* __restrict__ Xf, const float* __restrict__ Wf,
    const float* __restrict__ bias, float* __restrict__ C) {
  __shared__ unsigned short As[128][64];
  __shared__ unsigned short Bs[128][64];
  int tid = threadIdx.x;
  int lane = tid & 63;
  int wid = tid >> 6;
  int wr = wid >> 1, wc = wid & 1;
  int r0 = blockIdx.y * 128;
  int c0 = blockIdx.x * 128;
  f32x4 acc[4][4] = {};
  for (int kt = 0; kt < K_DIM / 64; ++kt) {
    __syncthreads();
    int ar = tid >> 1;
    int ac = (tid & 1) * 32;
    const float* xp = Xf + (size_t)(r0 + ar) * K_DIM + kt * 64 + ac;
#pragma unroll
    for (int jj = 0; jj < 8; ++jj) {
      f32x4 v = *(const f32x4*)(xp + jj * 4);
      As[ar][ac + jj * 4 + 0] = f32_to_bf16(v[0]);
      As[ar][ac + jj * 4 + 1] = f32_to_bf16(v[1]);
      As[ar][ac + jj * 4 + 2] = f32_to_bf16(v[2]);
      As[ar][ac + jj * 4 + 3] = f32_to_bf16(v[3]);
    }
    int bk_ = tid >> 2;
    int bc = (tid & 3) * 32;
    const float* wp = Wf + (size_t)(kt * 64 + bk_) * N_DIM + c0 + bc;
#pragma unroll
    for (int jj = 0; jj < 8; ++jj) {
      f32x4 v = *(const f32x4*)(wp + jj * 4);
      Bs[bc + jj * 4 + 0][bk_] = f32_to_bf16(v[0]);
      Bs[bc + jj * 4 + 1][bk_] = f32_to_bf16(v[1]);
      Bs[bc + jj * 4 + 2][bk_] = f32_to_bf16(v[2]);
      Bs[bc + jj * 4 + 3][bk_] = f32_to_bf16(v[3]);
    }
    __syncthreads();
#pragma unroll
    for (int ks = 0; ks < 2; ++ks) {
      int co = ks * 32 + (lane >> 4) * 8;
      int rA = wr * 64 + (lane & 15);
      int rB = wc * 64 + (lane & 15);
      short8 a[4], b[4];
#pragma unroll
      for (int m = 0; m < 4; ++m) a[m] = *(const short8*)&As[rA + m * 16][co];
#pragma unroll
      for (int n = 0; n < 4; ++n) b[n] = *(const short8*)&Bs[rB + n * 16][co];
#pragma unroll
      for (int m = 0; m < 4; ++m)
#pragma unroll
        for (int n = 0; n < 4; ++n)
          acc[m][n] = __builtin_amdgcn_mfma_f32_16x16x32_bf16(a[m], b[n], acc[m][n], 0, 0, 0);
    }
  }
  const float S = 65536.0f, IS = 1.0f / 65536.0f;
  int lr = (lane >> 4) * 4;
  int lc = lane & 15;
#pragma unroll
  for (int n = 0; n < 4; ++n) {
    int gcol = c0 + wc * 64 + n * 16 + lc;
    float bq = rintf(bias[gcol] * S) * IS;
#pragma unroll
    for (int m = 0; m < 4; ++m) {
      int grow = r0 + wr * 64 + m * 16 + lr;
      float* outp = C + (size_t)grow * N_DIM + gcol;
#pragma unroll
      for (int r = 0; r < 4; ++r) {
        float t = rintf(acc[m][n][r] * S) * IS + bq;
        t = t > 0.0f ? t : 0.0f;
        outp[(size_t)r * N_DIM] = t;
      }
    }
  }
}

extern "C" void kernel_launch(void* const* d_in, const int* in_sizes, int n_in,
                              void* d_out, int out_size, void* d_ws, size_t ws_size,
                              hipStream_t stream) {
  const float* x = (const float*)d_in[0];
  const float* w = (const float*)d_in[1];
  const float* b = (const float*)d_in[2];
  float* out = (float*)d_out;

  size_t needA = (size_t)M_DIM * K_DIM * sizeof(unsigned short);
  size_t needB = (size_t)K_DIM * N_DIM * sizeof(unsigned short);

  if (ws_size >= needA + needB) {
    unsigned short* Abf = (unsigned short*)d_ws;
    unsigned short* Btbf = (unsigned short*)((char*)d_ws + needA);
    prep_kernel<<<8192, 256, 0, stream>>>(x, Abf, w, Btbf);
    gemm8_kernel<<<256, 512, 0, stream>>>(Abf, Btbf, b, out);
  } else {
    gemm_fb_kernel<<<dim3(N_DIM / 128, M_DIM / 128), 256, 0, stream>>>(x, w, b, out);
  }
}